// Round 4
// baseline (186.117 us; speedup 1.0000x reference)
//
#include <hip/hip_runtime.h>
#include <hip/hip_bf16.h>
#include <cstdint>
#include <cstddef>

// Problem dims (fixed by the reference).
#define M_DIM 8192
#define K_DIM 2048
#define N_DIM 2048

// 256x256 8-phase template (HK-derived, guide §5).
#define BM 256
#define BN 256
#define BK 64
#define NITER (K_DIM / BK / 2)  // 16 iterations, 2 K-tiles each

typedef __bf16 bf16x8 __attribute__((ext_vector_type(8)));
typedef float f32x4 __attribute__((ext_vector_type(4)));
typedef unsigned short ushort8_t __attribute__((ext_vector_type(8)));

__device__ __forceinline__ unsigned short f32_to_bf16_rne(float f) {
  unsigned int u = __builtin_bit_cast(unsigned int, f);
  u += 0x7fffu + ((u >> 16) & 1u);
  return (unsigned short)(u >> 16);
}

// ---------------------------------------------------------------------------
// Fused conversion kernel (single launch):
//   blocks [0, 1024):   w (f32 [K,N]) -> wt (bf16 [N,K]) transpose, 64x64 tiles
//   blocks [1024, 3072): x (f32 [M,K]) -> xb (bf16 [M,K]), 8 elems/thread
// ---------------------------------------------------------------------------
__global__ void cvt_fused_kernel(const float* __restrict__ x,
                                 unsigned short* __restrict__ xb,
                                 const float* __restrict__ w,
                                 unsigned short* __restrict__ wt) {
  __shared__ float tile[64][65];
  if (blockIdx.x < 1024) {
    const int tx = threadIdx.x & 63;
    const int ty = threadIdx.x >> 6;  // 0..3
    const int n0 = (blockIdx.x & 31) * 64;
    const int k0 = (blockIdx.x >> 5) * 64;
#pragma unroll
    for (int r = 0; r < 16; ++r) {
      const int row = r * 4 + ty;  // k-local
      tile[row][tx] = w[(size_t)(k0 + row) * N_DIM + n0 + tx];
    }
    __syncthreads();
#pragma unroll
    for (int r = 0; r < 16; ++r) {
      const int row = r * 4 + ty;  // n-local
      wt[(size_t)(n0 + row) * K_DIM + k0 + tx] = f32_to_bf16_rne(tile[tx][row]);
    }
  } else {
    const size_t n = (size_t)M_DIM * K_DIM;
    size_t i = ((size_t)(blockIdx.x - 1024) * blockDim.x + threadIdx.x) * 8;
    const size_t stride = (size_t)2048 * blockDim.x * 8;
    for (; i < n; i += stride) {
      const float4 f0 = *reinterpret_cast<const float4*>(x + i);
      const float4 f1 = *reinterpret_cast<const float4*>(x + i + 4);
      ushort8_t o;
      o[0] = f32_to_bf16_rne(f0.x);
      o[1] = f32_to_bf16_rne(f0.y);
      o[2] = f32_to_bf16_rne(f0.z);
      o[3] = f32_to_bf16_rne(f0.w);
      o[4] = f32_to_bf16_rne(f1.x);
      o[5] = f32_to_bf16_rne(f1.y);
      o[6] = f32_to_bf16_rne(f1.z);
      o[7] = f32_to_bf16_rne(f1.w);
      *reinterpret_cast<ushort8_t*>(xb + i) = o;
    }
  }
}

// ---------------------------------------------------------------------------
// GEMM: 256x256 8-phase bf16. C[M,N] f32 = A[M,K] * Bt[N,K]^T.
// 8 waves (2M x 4N), per-wave 128x64 output. LDS 128 KiB double-buffered.
// Both-sides XOR swizzle: LDS slot s of row r holds global k-slot s^(r&7);
// staged linearly by global_load_lds from inverse-swizzled global addresses.
// ds_reads balanced {8,4,8,4+4} per half-iteration; B-reads for each Q00
// phase issued one phase early (overlapping the Q11 MFMA cluster).
// ---------------------------------------------------------------------------
__device__ __forceinline__ void async_copy16(unsigned short* lds_dst,
                                             const unsigned short* g_src) {
  __builtin_amdgcn_global_load_lds(
      (__attribute__((address_space(1))) void*)g_src,
      (__attribute__((address_space(3))) void*)lds_dst,
      16, 0, 0);
}

#define BARR() __builtin_amdgcn_s_barrier()
#define LGKM0()                                       \
  asm volatile("s_waitcnt lgkmcnt(0)" ::: "memory");  \
  __builtin_amdgcn_sched_barrier(0)
#define PRIO(p) __builtin_amdgcn_s_setprio(p)
#define VMCNT(n) asm volatile("s_waitcnt vmcnt(" #n ")" ::: "memory")

// Stage one half-tile (128 rows x 64 k) of A (isB=0) or B (isB=1), half h,
// K-tile t, into buf (t&1). 2 x global_load_lds(16B) per thread.
#define STG(isB, h, t)                                                       \
  do {                                                                       \
    const unsigned short* _src =                                             \
        ((isB) ? Bt : A) +                                                   \
        (size_t)(((isB) ? n0 : m0) + (h) * 128 + row0) * K_DIM + (t) * 64 +  \
        sg8;                                                                 \
    unsigned short* _dst = &smem[((t) & 1) * 32768 + (isB) * 16384 +         \
                                 (h) * 8192 + dst0];                         \
    async_copy16(_dst, _src);                                                \
    async_copy16(_dst + 4096, _src + 64 * K_DIM);                            \
  } while (0)

// ds_read the wave's A fragments for M-half moff (4 frags x 2 kslices).
#define RD_A(buf, moff)                                                      \
  do {                                                                       \
    _Pragma("unroll") for (int mf = 0; mf < 4; ++mf) {                       \
      const int _r = ((buf) * 32768) + (wm * 128 + ((moff) + mf) * 16 + lr) * 64; \
      a[mf][0] = *reinterpret_cast<const bf16x8*>(&smem[_r + sl0]);          \
      a[mf][1] = *reinterpret_cast<const bf16x8*>(&smem[_r + sl1]);          \
    }                                                                        \
  } while (0)

// ds_read the wave's B fragments for N-half noff into bdst (2 frags x 2 ks).
#define RD_B(bdst, buf, noff)                                                \
  do {                                                                       \
    _Pragma("unroll") for (int nf = 0; nf < 2; ++nf) {                       \
      const int _r = ((buf) * 32768) + 16384 +                               \
                     (wn * 64 + ((noff) + nf) * 16 + lr) * 64;               \
      bdst[nf][0] = *reinterpret_cast<const bf16x8*>(&smem[_r + sl0]);       \
      bdst[nf][1] = *reinterpret_cast<const bf16x8*>(&smem[_r + sl1]);       \
    }                                                                        \
  } while (0)

// 16 MFMA: one C-quadrant (4 m-frags x 2 n-frags x 2 kslices).
#define MM(bsel, moff, noff)                                                 \
  do {                                                                       \
    _Pragma("unroll") for (int mf = 0; mf < 4; ++mf) {                       \
      _Pragma("unroll") for (int nf = 0; nf < 2; ++nf) {                     \
        _Pragma("unroll") for (int ks = 0; ks < 2; ++ks) {                   \
          acc[(moff) + mf][(noff) + nf] =                                    \
              __builtin_amdgcn_mfma_f32_16x16x32_bf16(                       \
                  a[mf][ks], bsel[nf][ks], acc[(moff) + mf][(noff) + nf],    \
                  0, 0, 0);                                                  \
        }                                                                    \
      }                                                                      \
    }                                                                        \
  } while (0)

__global__ __launch_bounds__(512, 2) void gemm_kernel(
    const unsigned short* __restrict__ A,   // bf16 [M,K]
    const unsigned short* __restrict__ Bt,  // bf16 [N,K]
    float* __restrict__ C) {                // f32 [M,N]
  __shared__ unsigned short smem[2 * 32768];  // 128 KiB: [buf][A|B][256][64]

  const int tid = threadIdx.x;
  const int lane = tid & 63;
  const int wv = tid >> 6;          // 0..7
  const int wm = wv >> 2;           // 0..1
  const int wn = wv & 3;            // 0..3
  const int lr = lane & 15;
  const int kg = lane >> 4;         // 0..3
  // Swizzled ds_read slot offsets (elements): slot = (ks*4+kg) ^ (row&7),
  // and row&7 == lr&7 for all fragment rows.
  const int sl0 = ((kg ^ (lr & 7)) * 8);
  const int sl1 = (((kg + 4) ^ (lr & 7)) * 8);

  // XCD-aware chunked swizzle (nwg=256, divisible by 8).
  const int bid = blockIdx.x;
  const int wgid = (bid & 7) * 32 + (bid >> 3);
  const int bm = wgid >> 3;  // 0..31
  const int bn = wgid & 7;   // 0..7
  const int m0 = bm * BM;
  const int n0 = bn * BN;

  // Staging constants: thread covers chunks c = l*512 + tid (l=0,1);
  // row = c>>3, lds slot = c&7, global slot = (c&7) ^ (row&7).
  const int row0 = tid >> 3;                                  // 0..63
  const int sg8 = (((tid & 7) ^ ((tid >> 3) & 7)) * 8);       // global k-offset
  const int dst0 = wv * 512;  // wave-uniform LDS elem offset within region

  f32x4 acc[8][4] = {};
  bf16x8 a[4][2], b0[2][2], b1[2][2];

  // Prologue: tile0 fully + tile1 B halves; publish tile0; pre-read b0.
  STG(0, 0, 0); STG(0, 1, 0); STG(1, 0, 0); STG(1, 1, 0);
  STG(1, 0, 1); STG(1, 1, 1);
  VMCNT(4);  // tile0 arrived (tile1-B halves still in flight)
  BARR();
  RD_B(b0, 0, 0);  // drains at iter-0 P1's LGKM0

#pragma unroll 1
  for (int j = 0; j < NITER; ++j) {
    const int o = 2 * j + 1;  // odd K-tile -> buf1
    const int e2 = 2 * j + 2;
    const int o2 = 2 * j + 3;
    const bool more = (j + 1 < NITER);

    // ---- P1: Q00 of tile e (buf0) ----
    RD_A(0, 0);
    STG(0, 0, o);  // A-half0 of odd tile
    BARR(); LGKM0(); PRIO(1); MM(b0, 0, 0); PRIO(0); BARR();
    // ---- P2: Q01 ----
    RD_B(b1, 0, 2);
    STG(0, 1, o);  // A-half1 of odd tile
    BARR(); LGKM0(); PRIO(1); MM(b1, 0, 2); PRIO(0); BARR();
    // ---- P3: Q10 ----
    RD_A(0, 4);
    if (more) STG(1, 0, e2);  // B-half0 of tile e+2
    BARR(); LGKM0(); PRIO(1); MM(b0, 4, 0); PRIO(0); BARR();
    // ---- P4: Q11; publish tile o; pre-read its b0 ----
    if (more) {
      STG(1, 1, e2);  // B-half1 of tile e+2
      VMCNT(4);       // tile o fully arrived
    } else {
      VMCNT(0);
    }
    BARR();
    RD_B(b0, 1, 0);  // overlaps MM below; drains at P5's LGKM0
    PRIO(1); MM(b1, 4, 2); PRIO(0); BARR();

    // ---- P5: Q00 of tile o (buf1) ----
    RD_A(1, 0);
    if (more) STG(0, 0, e2);  // A-half0 of tile e+2
    BARR(); LGKM0(); PRIO(1); MM(b0, 0, 0); PRIO(0); BARR();
    // ---- P6: Q01 ----
    RD_B(b1, 1, 2);
    if (more) STG(0, 1, e2);  // A-half1 of tile e+2
    BARR(); LGKM0(); PRIO(1); MM(b1, 0, 2); PRIO(0); BARR();
    // ---- P7: Q10 ----
    RD_A(1, 4);
    if (more) STG(1, 0, o2);  // B-half0 of tile o+2
    BARR(); LGKM0(); PRIO(1); MM(b0, 4, 0); PRIO(0); BARR();
    // ---- P8: Q11; publish tile e+2; pre-read its b0 ----
    if (more) {
      STG(1, 1, o2);  // B-half1 of tile o+2
      VMCNT(4);       // tile e+2 fully arrived
    }
    BARR();
    if (more) RD_B(b0, 0, 0);  // drains at next-iter P1's LGKM0
    PRIO(1); MM(b1, 4, 2); PRIO(0); BARR();
  }

  // Epilogue: C/D layout col = lane&15, row = kg*4 + reg. Nontemporal (C is
  // never re-read; keep L2/L3 for A/B panels).
  const int crow0 = m0 + wm * 128 + kg * 4;
  const int ccol0 = n0 + wn * 64 + lr;
#pragma unroll
  for (int mi = 0; mi < 8; ++mi) {
#pragma unroll
    for (int ni = 0; ni < 4; ++ni) {
#pragma unroll
      for (int r = 0; r < 4; ++r) {
        __builtin_nontemporal_store(
            acc[mi][ni][r],
            &C[(size_t)(crow0 + mi * 16 + r) * N_DIM + ccol0 + ni * 16]);
      }
    }
  }
}

// ---------------------------------------------------------------------------
extern "C" void kernel_launch(void* const* d_in, const int* in_sizes, int n_in,
                              void* d_out, int out_size, void* d_ws,
                              size_t ws_size, hipStream_t stream) {
  const float* x = (const float*)d_in[0];  // [M,K] f32
  const float* w = (const float*)d_in[1];  // [K,N] f32
  float* out = (float*)d_out;              // [M,N] f32

  unsigned short* xb = (unsigned short*)d_ws;                         // 32 MiB
  unsigned short* wt = (unsigned short*)((char*)d_ws +
                                         (size_t)M_DIM * K_DIM * 2);  // 8 MiB

  cvt_fused_kernel<<<3072, 256, 0, stream>>>(x, xb, w, wt);

  const int grid = (M_DIM / BM) * (N_DIM / BN);  // 32 * 8 = 256
  gemm_kernel<<<grid, 512, 0, stream>>>(xb, wt, out);
}

// Round 6
// 179.605 us; speedup vs baseline: 1.0363x; 1.0363x over previous
//
#include <hip/hip_runtime.h>
#include <hip/hip_bf16.h>
#include <cstdint>
#include <cstddef>

// Problem dims (fixed by the reference).
#define M_DIM 8192
#define K_DIM 2048
#define N_DIM 2048

// 256x256 8-phase template (HK-derived, guide §5).
#define BM 256
#define BN 256
#define BK 64
#define NITER (K_DIM / BK / 2)  // 16 iterations, 2 K-tiles each

typedef __bf16 bf16x8 __attribute__((ext_vector_type(8)));
typedef float f32x4 __attribute__((ext_vector_type(4)));
typedef unsigned short ushort8_t __attribute__((ext_vector_type(8)));

__device__ __forceinline__ unsigned short f32_to_bf16_rne(float f) {
  unsigned int u = __builtin_bit_cast(unsigned int, f);
  u += 0x7fffu + ((u >> 16) & 1u);
  return (unsigned short)(u >> 16);
}

// ---------------------------------------------------------------------------
// Fused conversion kernel (single launch):
//   blocks [0, 1024):   w (f32 [K,N]) -> wt (bf16 [N,K]) transpose, 64x64 tiles
//   blocks [1024, 3072): x (f32 [M,K]) -> xb (bf16 [M,K]), 8 elems/thread
// ---------------------------------------------------------------------------
__global__ void cvt_fused_kernel(const float* __restrict__ x,
                                 unsigned short* __restrict__ xb,
                                 const float* __restrict__ w,
                                 unsigned short* __restrict__ wt) {
  __shared__ float tile[64][65];
  if (blockIdx.x < 1024) {
    const int tx = threadIdx.x & 63;
    const int ty = threadIdx.x >> 6;  // 0..3
    const int n0 = (blockIdx.x & 31) * 64;
    const int k0 = (blockIdx.x >> 5) * 64;
#pragma unroll
    for (int r = 0; r < 16; ++r) {
      const int row = r * 4 + ty;  // k-local
      tile[row][tx] = w[(size_t)(k0 + row) * N_DIM + n0 + tx];
    }
    __syncthreads();
#pragma unroll
    for (int r = 0; r < 16; ++r) {
      const int row = r * 4 + ty;  // n-local
      wt[(size_t)(n0 + row) * K_DIM + k0 + tx] = f32_to_bf16_rne(tile[tx][row]);
    }
  } else {
    const size_t n = (size_t)M_DIM * K_DIM;
    size_t i = ((size_t)(blockIdx.x - 1024) * blockDim.x + threadIdx.x) * 8;
    const size_t stride = (size_t)2048 * blockDim.x * 8;
    for (; i < n; i += stride) {
      const float4 f0 = *reinterpret_cast<const float4*>(x + i);
      const float4 f1 = *reinterpret_cast<const float4*>(x + i + 4);
      ushort8_t o;
      o[0] = f32_to_bf16_rne(f0.x);
      o[1] = f32_to_bf16_rne(f0.y);
      o[2] = f32_to_bf16_rne(f0.z);
      o[3] = f32_to_bf16_rne(f0.w);
      o[4] = f32_to_bf16_rne(f1.x);
      o[5] = f32_to_bf16_rne(f1.y);
      o[6] = f32_to_bf16_rne(f1.z);
      o[7] = f32_to_bf16_rne(f1.w);
      *reinterpret_cast<ushort8_t*>(xb + i) = o;
    }
  }
}

// ---------------------------------------------------------------------------
// GEMM: 256x256 8-phase bf16. C[M,N] f32 = A[M,K] * Bt[N,K]^T.
// 8 waves (2M x 4N), per-wave 128x64 output. LDS 128 KiB double-buffered.
// Both-sides XOR swizzle; linear global_load_lds dest + inverse-swizzled
// global source + swizzled ds_read.
// Staging: m201-faithful 3-deep lookahead — publishes at P4/P8 use vmcnt(6),
// draining loads that are >=3 phases old. Region-WAR verified:
//   B-halves of tile t restaged only after their last read (P2/P6),
//   A-halves after theirs (P3/P7); phase order per iter:
//   P1:+A1(o)  P3:+B0(e2)  P4:+B1,A0(e2)  P5:+A1(e2)  P7:+B0,B1(o2)  P8:+A0(o2)
// ---------------------------------------------------------------------------
__device__ __forceinline__ void async_copy16(unsigned short* lds_dst,
                                             const unsigned short* g_src) {
  __builtin_amdgcn_global_load_lds(
      (__attribute__((address_space(1))) void*)g_src,
      (__attribute__((address_space(3))) void*)lds_dst,
      16, 0, 0);
}

#define BARR() __builtin_amdgcn_s_barrier()
#define LGKM0()                                       \
  asm volatile("s_waitcnt lgkmcnt(0)" ::: "memory");  \
  __builtin_amdgcn_sched_barrier(0)
#define PRIO(p) __builtin_amdgcn_s_setprio(p)
#define VMCNT(n) asm volatile("s_waitcnt vmcnt(" #n ")" ::: "memory")

// Stage one half-tile (128 rows x 64 k) of A (isB=0) or B (isB=1), half h,
// K-tile t, into buf (t&1). 2 x global_load_lds(16B) per thread.
#define STG(isB, h, t)                                                       \
  do {                                                                       \
    const unsigned short* _src =                                             \
        ((isB) ? Bt : A) +                                                   \
        (size_t)(((isB) ? n0 : m0) + (h) * 128 + row0) * K_DIM + (t) * 64 +  \
        sg8;                                                                 \
    unsigned short* _dst = &smem[((t) & 1) * 32768 + (isB) * 16384 +         \
                                 (h) * 8192 + dst0];                         \
    async_copy16(_dst, _src);                                                \
    async_copy16(_dst + 4096, _src + 64 * K_DIM);                            \
  } while (0)

// ds_read the wave's A fragments for M-half moff (4 frags x 2 kslices).
#define RD_A(buf, moff)                                                      \
  do {                                                                       \
    _Pragma("unroll") for (int mf = 0; mf < 4; ++mf) {                       \
      const int _r = ((buf) * 32768) + (wm * 128 + ((moff) + mf) * 16 + lr) * 64; \
      a[mf][0] = *reinterpret_cast<const bf16x8*>(&smem[_r + sl0]);          \
      a[mf][1] = *reinterpret_cast<const bf16x8*>(&smem[_r + sl1]);          \
    }                                                                        \
  } while (0)

// ds_read the wave's B fragments for N-half noff into bdst (2 frags x 2 ks).
#define RD_B(bdst, buf, noff)                                                \
  do {                                                                       \
    _Pragma("unroll") for (int nf = 0; nf < 2; ++nf) {                       \
      const int _r = ((buf) * 32768) + 16384 +                               \
                     (wn * 64 + ((noff) + nf) * 16 + lr) * 64;               \
      bdst[nf][0] = *reinterpret_cast<const bf16x8*>(&smem[_r + sl0]);       \
      bdst[nf][1] = *reinterpret_cast<const bf16x8*>(&smem[_r + sl1]);       \
    }                                                                        \
  } while (0)

// 16 MFMA: one C-quadrant (4 m-frags x 2 n-frags x 2 kslices).
#define MM(bsel, moff, noff)                                                 \
  do {                                                                       \
    _Pragma("unroll") for (int mf = 0; mf < 4; ++mf) {                       \
      _Pragma("unroll") for (int nf = 0; nf < 2; ++nf) {                     \
        _Pragma("unroll") for (int ks = 0; ks < 2; ++ks) {                   \
          acc[(moff) + mf][(noff) + nf] =                                    \
              __builtin_amdgcn_mfma_f32_16x16x32_bf16(                       \
                  a[mf][ks], bsel[nf][ks], acc[(moff) + mf][(noff) + nf],    \
                  0, 0, 0);                                                  \
        }                                                                    \
      }                                                                      \
    }                                                                        \
  } while (0)

__global__ __launch_bounds__(512, 2) void gemm_kernel(
    const unsigned short* __restrict__ A,   // bf16 [M,K]
    const unsigned short* __restrict__ Bt,  // bf16 [N,K]
    float* __restrict__ C) {                // f32 [M,N]
  __shared__ unsigned short smem[2 * 32768];  // 128 KiB: [buf][A|B][256][64]

  const int tid = threadIdx.x;
  const int lane = tid & 63;
  const int wv = tid >> 6;          // 0..7
  const int wm = wv >> 2;           // 0..1
  const int wn = wv & 3;            // 0..3
  const int lr = lane & 15;
  const int kg = lane >> 4;         // 0..3
  // Swizzled ds_read slot offsets (elements): slot = (ks*4+kg) ^ (row&7),
  // and row&7 == lr&7 for all fragment rows.
  const int sl0 = ((kg ^ (lr & 7)) * 8);
  const int sl1 = (((kg + 4) ^ (lr & 7)) * 8);

  // XCD-aware chunked swizzle (nwg=256, divisible by 8). Same-bm blocks land
  // on one XCD -> A-panel L2 reuse.
  const int bid = blockIdx.x;
  const int wgid = (bid & 7) * 32 + (bid >> 3);
  const int bm = wgid >> 3;  // 0..31
  const int bn = wgid & 7;   // 0..7
  const int m0 = bm * BM;
  const int n0 = bn * BN;

  // Staging constants: thread covers chunks c = l*512 + tid (l=0,1);
  // row = c>>3, lds slot = c&7, global slot = (c&7) ^ (row&7).
  const int row0 = tid >> 3;                                  // 0..63
  const int sg8 = (((tid & 7) ^ ((tid >> 3) & 7)) * 8);       // global k-offset
  const int dst0 = wv * 512;  // wave-uniform LDS elem offset within region

  f32x4 acc[8][4] = {};
  bf16x8 a[4][2], b0[2][2], b1[2][2];

  // Prologue: tile0 all 4 halves + tile1 {B0, B1, A0}; publish tile0 with
  // vmcnt(6) (tile1's 3 halves stay in flight); pre-read b0 of tile0.
  STG(0, 0, 0); STG(0, 1, 0); STG(1, 0, 0); STG(1, 1, 0);
  STG(1, 0, 1); STG(1, 1, 1); STG(0, 0, 1);
  VMCNT(6);
  BARR();
  RD_B(b0, 0, 0);  // drains at iter-0 P1's LGKM0

#pragma unroll 1
  for (int j = 0; j < NITER; ++j) {
    const int o = 2 * j + 1;  // odd K-tile -> buf1
    const int e2 = 2 * j + 2;
    const int o2 = 2 * j + 3;
    const bool more = (j + 1 < NITER);

    // ---- P1: Q00 of tile e (buf0); stage A1 of o ----
    RD_A(0, 0);
    STG(0, 1, o);
    BARR(); LGKM0(); PRIO(1); MM(b0, 0, 0); PRIO(0); BARR();
    // ---- P2: Q01 (no staging) ----
    RD_B(b1, 0, 2);
    BARR(); LGKM0(); PRIO(1); MM(b1, 0, 2); PRIO(0); BARR();
    // ---- P3: Q10; stage B0 of e2 (B of e last read at P2) ----
    RD_A(0, 4);
    if (more) STG(1, 0, e2);
    BARR(); LGKM0(); PRIO(1); MM(b0, 4, 0); PRIO(0); BARR();
    // ---- P4: Q11; stage B1,A0 of e2; publish tile o (vmcnt 6) ----
    if (more) {
      STG(1, 1, e2);
      STG(0, 0, e2);
      VMCNT(6);  // leaves P3/P4's 3 halves; drains A1(o) staged 3 phases ago
    } else {
      VMCNT(0);
    }
    BARR();
    RD_B(b0, 1, 0);  // overlaps MM; drains at P5's LGKM0
    PRIO(1); MM(b1, 4, 2); PRIO(0); BARR();

    // ---- P5: Q00 of tile o (buf1); stage A1 of e2 (A of e last read P3) ----
    RD_A(1, 0);
    if (more) STG(0, 1, e2);
    BARR(); LGKM0(); PRIO(1); MM(b0, 0, 0); PRIO(0); BARR();
    // ---- P6: Q01 (no staging; B of o read here) ----
    RD_B(b1, 1, 2);
    BARR(); LGKM0(); PRIO(1); MM(b1, 0, 2); PRIO(0); BARR();
    // ---- P7: Q10; stage B0,B1 of o2 (B of o last read at P6) ----
    RD_A(1, 4);
    if (more) { STG(1, 0, o2); STG(1, 1, o2); }
    BARR(); LGKM0(); PRIO(1); MM(b0, 4, 0); PRIO(0); BARR();
    // ---- P8: Q11; stage A0 of o2 (A of o last read at P7); publish e2 ----
    if (more) {
      STG(0, 0, o2);
      VMCNT(6);  // leaves P7/P8's 3 halves; drains A1(e2) staged 3 phases ago
    }
    BARR();
    if (more) RD_B(b0, 0, 0);  // drains at next-iter P1's LGKM0
    PRIO(1); MM(b1, 4, 2); PRIO(0); BARR();
  }

  // Epilogue: C/D layout col = lane&15, row = kg*4 + reg. Plain stores —
  // nontemporal regressed (WRITE_SIZE 64->84 MB, partial-line HBM writes).
  const int crow0 = m0 + wm * 128 + kg * 4;
  const int ccol0 = n0 + wn * 64 + lr;
#pragma unroll
  for (int mi = 0; mi < 8; ++mi) {
#pragma unroll
    for (int ni = 0; ni < 4; ++ni) {
#pragma unroll
      for (int r = 0; r < 4; ++r) {
        C[(size_t)(crow0 + mi * 16 + r) * N_DIM + ccol0 + ni * 16] =
            acc[mi][ni][r];
      }
    }
  }
}

// ---------------------------------------------------------------------------
extern "C" void kernel_launch(void* const* d_in, const int* in_sizes, int n_in,
                              void* d_out, int out_size, void* d_ws,
                              size_t ws_size, hipStream_t stream) {
  const float* x = (const float*)d_in[0];  // [M,K] f32
  const float* w = (const float*)d_in[1];  // [K,N] f32
  float* out = (float*)d_out;              // [M,N] f32

  unsigned short* xb = (unsigned short*)d_ws;                         // 32 MiB
  unsigned short* wt = (unsigned short*)((char*)d_ws +
                                         (size_t)M_DIM * K_DIM * 2);  // 8 MiB

  cvt_fused_kernel<<<3072, 256, 0, stream>>>(x, xb, w, wt);

  const int grid = (M_DIM / BM) * (N_DIM / BN);  // 32 * 8 = 256
  gemm_kernel<<<grid, 512, 0, stream>>>(xb, wt, out);
}

// Round 8
// 177.300 us; speedup vs baseline: 1.0497x; 1.0130x over previous
//
#include <hip/hip_runtime.h>
#include <hip/hip_bf16.h>
#include <cstdint>
#include <cstddef>

// Problem dims (fixed by the reference).
#define M_DIM 8192
#define K_DIM 2048
#define N_DIM 2048

// 256x256 tile, BK=64, 8 waves. 6-phase merged schedule (this round).
#define BM 256
#define BN 256
#define BK 64
#define NITER (K_DIM / BK / 2)  // 16 iterations, 2 K-tiles each

typedef __bf16 bf16x8 __attribute__((ext_vector_type(8)));
typedef float f32x4 __attribute__((ext_vector_type(4)));
typedef unsigned short ushort8_t __attribute__((ext_vector_type(8)));

__device__ __forceinline__ unsigned short f32_to_bf16_rne(float f) {
  unsigned int u = __builtin_bit_cast(unsigned int, f);
  u += 0x7fffu + ((u >> 16) & 1u);
  return (unsigned short)(u >> 16);
}

// ---------------------------------------------------------------------------
// Fused conversion kernel (single launch):
//   blocks [0, 1024):   w (f32 [K,N]) -> wt (bf16 [N,K]) transpose, 64x64 tiles
//   blocks [1024, 3072): x (f32 [M,K]) -> xb (bf16 [M,K]), 8 elems/thread
// ---------------------------------------------------------------------------
__global__ void cvt_fused_kernel(const float* __restrict__ x,
                                 unsigned short* __restrict__ xb,
                                 const float* __restrict__ w,
                                 unsigned short* __restrict__ wt) {
  __shared__ float tile[64][65];
  if (blockIdx.x < 1024) {
    const int tx = threadIdx.x & 63;
    const int ty = threadIdx.x >> 6;  // 0..3
    const int n0 = (blockIdx.x & 31) * 64;
    const int k0 = (blockIdx.x >> 5) * 64;
#pragma unroll
    for (int r = 0; r < 16; ++r) {
      const int row = r * 4 + ty;  // k-local
      tile[row][tx] = w[(size_t)(k0 + row) * N_DIM + n0 + tx];
    }
    __syncthreads();
#pragma unroll
    for (int r = 0; r < 16; ++r) {
      const int row = r * 4 + ty;  // n-local
      wt[(size_t)(n0 + row) * K_DIM + k0 + tx] = f32_to_bf16_rne(tile[tx][row]);
    }
  } else {
    const size_t n = (size_t)M_DIM * K_DIM;
    size_t i = ((size_t)(blockIdx.x - 1024) * blockDim.x + threadIdx.x) * 8;
    const size_t stride = (size_t)2048 * blockDim.x * 8;
    for (; i < n; i += stride) {
      const float4 f0 = *reinterpret_cast<const float4*>(x + i);
      const float4 f1 = *reinterpret_cast<const float4*>(x + i + 4);
      ushort8_t o;
      o[0] = f32_to_bf16_rne(f0.x);
      o[1] = f32_to_bf16_rne(f0.y);
      o[2] = f32_to_bf16_rne(f0.z);
      o[3] = f32_to_bf16_rne(f0.w);
      o[4] = f32_to_bf16_rne(f1.x);
      o[5] = f32_to_bf16_rne(f1.y);
      o[6] = f32_to_bf16_rne(f1.z);
      o[7] = f32_to_bf16_rne(f1.w);
      *reinterpret_cast<ushort8_t*>(xb + i) = o;
    }
  }
}

// ---------------------------------------------------------------------------
// GEMM: 256x256 bf16, 6-phase merged schedule. C[M,N] f32 = A[M,K]*Bt[N,K]^T.
// Theory (R6 post-mortem): the 8-phase's 16 barriers/iter serialized the
// per-phase LDS burst (512 cyc) against the MFMA burst (621 cyc). This
// schedule has 8 barriers/iter; all B-fragment ds_reads issue inside MFMA
// windows; A-reads stay in pre-slots but get longer windows to stagger into.
// Per-iter staging ledger (each tile = 4 halves = 8 gl_lds ops/wave):
//   F1: A0,A1(o)   F3: B0,B1(e2)   F4: A0,A1(e2)   F6: B0,B1(o2)
// Publishes: F3-mid VMCNT(4) (tile o = 8 oldest ops), F6-mid VMCNT(4)
// (tile e2). WAR: every restage placed after the barrier following its
// region's last-drain LGKM0 (verified per phase).
// ---------------------------------------------------------------------------
__device__ __forceinline__ void async_copy16(unsigned short* lds_dst,
                                             const unsigned short* g_src) {
  __builtin_amdgcn_global_load_lds(
      (__attribute__((address_space(1))) void*)g_src,
      (__attribute__((address_space(3))) void*)lds_dst,
      16, 0, 0);
}

#define BARR() __builtin_amdgcn_s_barrier()
#define LGKM0()                                       \
  asm volatile("s_waitcnt lgkmcnt(0)" ::: "memory");  \
  __builtin_amdgcn_sched_barrier(0)
#define PRIO(p) __builtin_amdgcn_s_setprio(p)
#define VMCNT(n) asm volatile("s_waitcnt vmcnt(" #n ")" ::: "memory")

// Stage one half-tile (128 rows x 64 k) of A (isB=0) or B (isB=1), half h,
// K-tile t, into buf (t&1). 2 x global_load_lds(16B) per thread.
#define STG(isB, h, t)                                                       \
  do {                                                                       \
    const unsigned short* _src =                                             \
        ((isB) ? Bt : A) +                                                   \
        (size_t)(((isB) ? n0 : m0) + (h) * 128 + row0) * K_DIM + (t) * 64 +  \
        sg8;                                                                 \
    unsigned short* _dst = &smem[((t) & 1) * 32768 + (isB) * 16384 +         \
                                 (h) * 8192 + dst0];                         \
    async_copy16(_dst, _src);                                                \
    async_copy16(_dst + 4096, _src + 64 * K_DIM);                            \
  } while (0)

// ds_read the wave's A fragments for M-half moff (4 frags x 2 kslices).
#define RD_A(buf, moff)                                                      \
  do {                                                                       \
    _Pragma("unroll") for (int mf = 0; mf < 4; ++mf) {                       \
      const int _r = ((buf) * 32768) + (wm * 128 + ((moff) + mf) * 16 + lr) * 64; \
      a[mf][0] = *reinterpret_cast<const bf16x8*>(&smem[_r + sl0]);          \
      a[mf][1] = *reinterpret_cast<const bf16x8*>(&smem[_r + sl1]);          \
    }                                                                        \
  } while (0)

// ds_read the wave's B fragments for N-half noff into bdst (2 frags x 2 ks).
#define RD_B(bdst, buf, noff)                                                \
  do {                                                                       \
    _Pragma("unroll") for (int nf = 0; nf < 2; ++nf) {                       \
      const int _r = ((buf) * 32768) + 16384 +                               \
                     (wn * 64 + ((noff) + nf) * 16 + lr) * 64;               \
      bdst[nf][0] = *reinterpret_cast<const bf16x8*>(&smem[_r + sl0]);       \
      bdst[nf][1] = *reinterpret_cast<const bf16x8*>(&smem[_r + sl1]);       \
    }                                                                        \
  } while (0)

// 16 MFMA: one C-quadrant (4 m-frags x 2 n-frags x 2 kslices).
#define MM(bsel, moff, noff)                                                 \
  do {                                                                       \
    _Pragma("unroll") for (int mf = 0; mf < 4; ++mf) {                       \
      _Pragma("unroll") for (int nf = 0; nf < 2; ++nf) {                     \
        _Pragma("unroll") for (int ks = 0; ks < 2; ++ks) {                   \
          acc[(moff) + mf][(noff) + nf] =                                    \
              __builtin_amdgcn_mfma_f32_16x16x32_bf16(                       \
                  a[mf][ks], bsel[nf][ks], acc[(moff) + mf][(noff) + nf],    \
                  0, 0, 0);                                                  \
        }                                                                    \
      }                                                                      \
    }                                                                        \
  } while (0)

__global__ __launch_bounds__(512, 2) void gemm_kernel(
    const unsigned short* __restrict__ A,   // bf16 [M,K]
    const unsigned short* __restrict__ Bt,  // bf16 [N,K]
    float* __restrict__ C) {                // f32 [M,N]
  __shared__ unsigned short smem[2 * 32768];  // 128 KiB: [buf][A|B][256][64]

  const int tid = threadIdx.x;
  const int lane = tid & 63;
  const int wv = tid >> 6;          // 0..7
  const int wm = wv >> 2;           // 0..1
  const int wn = wv & 3;            // 0..3
  const int lr = lane & 15;
  const int kg = lane >> 4;         // 0..3
  // Swizzled ds_read slot offsets (elements): slot = (ks*4+kg) ^ (row&7),
  // and row&7 == lr&7 for all fragment rows.
  const int sl0 = ((kg ^ (lr & 7)) * 8);
  const int sl1 = (((kg + 4) ^ (lr & 7)) * 8);

  // XCD-aware chunked swizzle (nwg=256, divisible by 8).
  const int bid = blockIdx.x;
  const int wgid = (bid & 7) * 32 + (bid >> 3);
  const int bm = wgid >> 3;  // 0..31
  const int bn = wgid & 7;   // 0..7
  const int m0 = bm * BM;
  const int n0 = bn * BN;

  // Staging constants: thread covers chunks c = l*512 + tid (l=0,1);
  // row = c>>3, lds slot = c&7, global slot = (c&7) ^ (row&7).
  const int row0 = tid >> 3;                                  // 0..63
  const int sg8 = (((tid & 7) ^ ((tid >> 3) & 7)) * 8);       // global k-offset
  const int dst0 = wv * 512;  // wave-uniform LDS elem offset within region

  f32x4 acc[8][4] = {};
  bf16x8 a[4][2], b0[2][2], b1[2][2];

  // Prologue: tile0 all 4 halves + tile1 B halves; publish tile0 with
  // VMCNT(4) (tile1's B stays in flight); window-read b0 of tile0.
  STG(0, 0, 0); STG(0, 1, 0); STG(1, 0, 0); STG(1, 1, 0);
  STG(1, 0, 1); STG(1, 1, 1);
  VMCNT(4);
  BARR();
  RD_B(b0, 0, 0);  // drains at iter-0 F1's LGKM0

#pragma unroll 1
  for (int j = 0; j < NITER; ++j) {
    const int o = 2 * j + 1;  // odd K-tile -> buf1
    const int e2 = 2 * j + 2;
    const int o2 = 2 * j + 3;
    const bool more = (j + 1 < NITER);

    // ==== F1: Q00(e). Stage A0,A1(o) (buf1-A free since prev F6-exit). ====
    RD_A(0, 0);
    STG(0, 0, o); STG(0, 1, o);
    LGKM0();                 // drains b0-window + a_lo
    RD_B(b1, 0, 2);          // window: b1(e) for F2
    PRIO(1); MM(b0, 0, 0); PRIO(0);
    BARR();                  // F1-exit

    // ==== F2: Q01(e). Pure MFMA. ====
    LGKM0();                 // drains b1(e)
    PRIO(1); MM(b1, 0, 2); PRIO(0);
    BARR();                  // F2-exit (gates F3's B-restage vs b1 reads)

    // ==== F3: Q10+Q11(e). Stage B0,B1(e2); publish tile o. ====
    RD_A(0, 4);
    if (more) { STG(1, 0, e2); STG(1, 1, e2); }
    if (more) { VMCNT(4); } else { VMCNT(0); }  // drain A+B of tile o
    BARR();                  // F3-mid: PUBLISH tile o
    LGKM0();                 // drains a_hi
    PRIO(1); MM(b0, 4, 0); PRIO(0);
    RD_B(b0, 1, 0);          // window: b0(o); b0(e) dead after MM above
    PRIO(1); MM(b1, 4, 2); PRIO(0);
    BARR();                  // F3-exit

    // ==== F4: Q00(o). Stage A0,A1(e2) (buf0-A reads drained at F3). ====
    RD_A(1, 0);
    if (more) { STG(0, 0, e2); STG(0, 1, e2); }
    LGKM0();                 // drains b0(o)-window + a_lo
    RD_B(b1, 1, 2);          // window: b1(o) for F5
    PRIO(1); MM(b0, 0, 0); PRIO(0);
    BARR();                  // F4-exit

    // ==== F5: Q01(o). Pure MFMA. ====
    LGKM0();
    PRIO(1); MM(b1, 0, 2); PRIO(0);
    BARR();                  // F5-exit (gates F6's B-restage vs b1(o) reads)

    // ==== F6: Q10+Q11(o). Stage B0,B1(o2); publish tile e2. ====
    RD_A(1, 4);
    if (more) { STG(1, 0, o2); STG(1, 1, o2); }
    if (more) { VMCNT(4); } else { VMCNT(0); }  // drain A+B of tile e2
    BARR();                  // F6-mid: PUBLISH tile e2
    LGKM0();                 // drains a_hi(o)
    PRIO(1); MM(b0, 4, 0); PRIO(0);
    if (more) RD_B(b0, 0, 0);  // window: b0(e2) for next F1
    PRIO(1); MM(b1, 4, 2); PRIO(0);
    BARR();                  // F6-exit
  }

  // Epilogue: C/D layout col = lane&15, row = kg*4 + reg. Plain stores
  // (nontemporal regressed: partial-line HBM writes, WRITE 64->84 MB).
  const int crow0 = m0 + wm * 128 + kg * 4;
  const int ccol0 = n0 + wn * 64 + lr;
#pragma unroll
  for (int mi = 0; mi < 8; ++mi) {
#pragma unroll
    for (int ni = 0; ni < 4; ++ni) {
#pragma unroll
      for (int r = 0; r < 4; ++r) {
        C[(size_t)(crow0 + mi * 16 + r) * N_DIM + ccol0 + ni * 16] =
            acc[mi][ni][r];
      }
    }
  }
}

// ---------------------------------------------------------------------------
extern "C" void kernel_launch(void* const* d_in, const int* in_sizes, int n_in,
                              void* d_out, int out_size, void* d_ws,
                              size_t ws_size, hipStream_t stream) {
  const float* x = (const float*)d_in[0];  // [M,K] f32
  const float* w = (const float*)d_in[1];  // [K,N] f32
  float* out = (float*)d_out;              // [M,N] f32

  unsigned short* xb = (unsigned short*)d_ws;                         // 32 MiB
  unsigned short* wt = (unsigned short*)((char*)d_ws +
                                         (size_t)M_DIM * K_DIM * 2);  // 8 MiB

  cvt_fused_kernel<<<3072, 256, 0, stream>>>(x, xb, w, wt);

  const int grid = (M_DIM / BM) * (N_DIM / BN);  // 32 * 8 = 256
  gemm_kernel<<<grid, 512, 0, stream>>>(xb, wt, out);
}